// Round 6
// baseline (645.289 us; speedup 1.0000x reference)
//
#include <hip/hip_runtime.h>
#include <hip/hip_bf16.h>

#define N_NODES 50000
#define KK 32
#define EE 128
#define NK (N_NODES * KK)
#define NE (N_NODES * EE)
#define TN 16
#define WAVES 4

typedef __hip_bfloat16 bf16;
typedef unsigned int u32;
typedef unsigned short u16;

// bf16x2 packed in a dword: lo = element 2*lane, hi = element 2*lane+1
__device__ __forceinline__ float bflo(u32 u) { return __uint_as_float(u << 16); }
__device__ __forceinline__ float bfhi(u32 u) { return __uint_as_float(u & 0xFFFF0000u); }
__device__ __forceinline__ u16 f2bu(float x) {
    union { bf16 b; u16 u; } c; c.b = __float2bfloat16(x); return c.u;
}
__device__ __forceinline__ u32 packbf2(float lo, float hi) {
    return (u32)f2bu(lo) | ((u32)f2bu(hi) << 16);
}

// ---------------------------------------------------------------------------
// Prep: y==0 -> A = WhL@Wf, B = WhR@Wf (column-major [c][r]) + ag/bh2 biases;
//       y==1 -> transpose Ws [128][256] -> Wst [256][128].
// grid (256,2), block 128.
// ---------------------------------------------------------------------------
__global__ void prep_weights(const float* __restrict__ Wh, const float* __restrict__ Wf,
                             const float* __restrict__ bfv, const float* __restrict__ bh,
                             const float* __restrict__ Ws,
                             float* Acm, float* Bcm, float* agf, float* bh2f, float* Wst) {
    int bx = blockIdx.x;
    if (blockIdx.y == 1) {   // transpose Ws: c = bx in [0,256)
        int r = threadIdx.x;
        Wst[bx * EE + r] = Ws[(long)r * (2 * EE) + bx];
        return;
    }
    int m = bx >> 7;         // 0 = left half of Wh, 1 = right half
    int r = bx & 127;        // output channel
    int c = threadIdx.x;     // input channel
    const float* whrow = Wh + (long)r * (2 * EE) + m * EE;
    float acc = 0.f;
    for (int j = 0; j < EE; ++j)
        acc += whrow[j] * Wf[(long)j * EE + c];
    float* dst = m ? Bcm : Acm;
    dst[c * EE + r] = acc;
    if (c == 0) {
        float accb = 0.f;
        for (int j = 0; j < EE; ++j) accb += whrow[j] * bfv[j];
        if (m) bh2f[r] = accb + bh[r];
        else   agf[r] = accb;
    }
}

// ---------------------------------------------------------------------------
// Distance MLP: d(x) = sum_e W2[e]*relu(W1[e]*x + b1[e]) + b2.
// d written f32 into the out_position region of d_out.
// ---------------------------------------------------------------------------
__global__ __launch_bounds__(256) void dist_mlp(const float* __restrict__ dists,
                                                const float* __restrict__ W1,
                                                const float* __restrict__ b1,
                                                const float* __restrict__ W2,
                                                const float* __restrict__ b2v,
                                                float* __restrict__ dst) {
    __shared__ float4 w4[EE];
    int tid = threadIdx.x;
    if (tid < EE) w4[tid] = make_float4(W1[tid], b1[tid], W2[tid], 0.f);
    __syncthreads();
    float b2s = b2v[0];
    int i0 = (blockIdx.x * 256 + tid) * 4;
    float x[4], acc[4];
    #pragma unroll
    for (int j = 0; j < 4; ++j) {
        int i = i0 + j;
        x[j] = (i < NK) ? dists[i] : 0.f;
        acc[j] = b2s;
    }
    for (int e = 0; e < EE; ++e) {
        float4 w = w4[e];
        #pragma unroll
        for (int j = 0; j < 4; ++j)
            acc[j] += w.z * fmaxf(w.x * x[j] + w.y, 0.f);
    }
    #pragma unroll
    for (int j = 0; j < 4; ++j) {
        int i = i0 + j;
        if (i < NK) dst[i] = acc[j];
    }
}

// ---------------------------------------------------------------------------
// g = feature@A^T + ag, h2 = feature@B^T + bh2, both bf16, packed into the
// out_structure region of d_out. grid N/TN, block 128.
// ---------------------------------------------------------------------------
__global__ __launch_bounds__(128) void proj_gh(const float* __restrict__ feature,
                                               const float* __restrict__ Acm,
                                               const float* __restrict__ Bcm,
                                               const float* __restrict__ agf,
                                               const float* __restrict__ bh2f,
                                               u16* __restrict__ g, u16* __restrict__ h2) {
    __shared__ float fl[TN][EE];
    int r = threadIdx.x;
    int n0 = blockIdx.x * TN;
    for (int n = 0; n < TN; ++n)
        fl[n][r] = feature[(long)(n0 + n) * EE + r];
    __syncthreads();
    float accg[TN], acch[TN];
    float ag = agf[r], bh = bh2f[r];
    #pragma unroll
    for (int n = 0; n < TN; ++n) { accg[n] = ag; acch[n] = bh; }
    for (int c = 0; c < EE; ++c) {
        float a = Acm[c * EE + r];
        float b = Bcm[c * EE + r];
        #pragma unroll
        for (int n = 0; n < TN; ++n) {
            float f = fl[n][c];
            accg[n] += f * a;
            acch[n] += f * b;
        }
    }
    for (int n = 0; n < TN; ++n) {
        g [(long)(n0 + n) * EE + r] = f2bu(accg[n]);
        h2[(long)(n0 + n) * EE + r] = f2bu(acch[n]);
    }
}

// ---------------------------------------------------------------------------
// Fused gather + relu + Wp-dot + mean. One wave per node; lane handles
// channels (2*lane, 2*lane+1) -> one dword gather per (k, lane).
// n forced wave-uniform so argmax/d reads become scalar loads (no shfl
// broadcasts); Wp-dot deferred into pp[32] then one halving exchange tree
// (32 shfls total, vs 192 for per-k butterflies). grid N/4, block 256.
// ---------------------------------------------------------------------------
__global__ __launch_bounds__(256) void fused_msg(const int* __restrict__ argmax,
                                                 const u32* __restrict__ g,
                                                 const u32* __restrict__ h2,
                                                 const float* __restrict__ Wp,
                                                 const float* __restrict__ bpv,
                                                 float* outpos,
                                                 u32* __restrict__ meanws) {
    int tid = threadIdx.x;
    int lane = tid & 63;
    int n = __builtin_amdgcn_readfirstlane(blockIdx.x * WAVES + (tid >> 6));

    const int* arow = argmax + (long)n * KK;     // wave-uniform base
    const float* drow = outpos + (long)n * KK;   // d values (written by dist_mlp)

    u32 hu = h2[(long)n * (EE / 2) + lane];
    float h0 = bflo(hu), h1 = bfhi(hu);
    float2 wpv = ((const float2*)Wp)[lane];
    float bpf = bpv[0];

    float acc0 = 0.f, acc1 = 0.f;
    float pp[KK];
    #pragma unroll 8
    for (int k = 0; k < KK; ++k) {
        int row = arow[k];        // uniform address -> s_load
        float dk = drow[k];       // uniform address -> s_load
        u32 gu = g[(long)row * (EE / 2) + lane];
        float m0 = fmaxf(dk * bflo(gu) + h0, 0.f);
        float m1 = fmaxf(dk * bfhi(gu) + h1, 0.f);
        acc0 += m0;
        acc1 += m1;
        pp[k] = fmaf(m1, wpv.y, m0 * wpv.x);
    }
    meanws[(long)n * (EE / 2) + lane] = packbf2(acc0 * (1.f / KK), acc1 * (1.f / KK));

    // Halving exchange: 32 values/lane -> 1 value/lane, k = bitrev5(lane&31).
    int cnt = KK;
    #pragma unroll
    for (int s = 1; s <= 32; s <<= 1) {
        if (cnt > 1) {
            int half = cnt >> 1;
            bool hi = (lane & s) != 0;
            #pragma unroll
            for (int i = 0; i < KK / 2; ++i) {   // bounded; only i<half live
                if (i < half) {
                    float give = hi ? pp[i] : pp[half + i];
                    float keep = hi ? pp[half + i] : pp[i];
                    pp[i] = keep + __shfl_xor(give, s);
                }
            }
            cnt = half;
        } else {
            pp[0] += __shfl_xor(pp[0], s);
        }
    }
    if (lane < KK) {
        int kk = ((lane & 1) << 4) | ((lane & 2) << 2) | (lane & 4)
               | ((lane & 8) >> 2) | ((lane & 16) >> 4);
        outpos[(long)n * KK + kk] = pp[0] + bpf;
    }
}

// ---------------------------------------------------------------------------
// out_structure = [mean | edge_attr] @ Ws^T + bs -> f32, overwrites the
// out_structure region (g/h2 dead). grid N/TN, block 128.
// ---------------------------------------------------------------------------
__global__ __launch_bounds__(128) void out_struct(const u16* __restrict__ meanws,
                                                  const float* __restrict__ edge_attr,
                                                  const float* __restrict__ Wst,
                                                  const float* __restrict__ bs,
                                                  float* __restrict__ outs) {
    __shared__ float mm[TN][EE];
    __shared__ float ea[TN][EE];
    int r = threadIdx.x;
    int n0 = blockIdx.x * TN;
    for (int n = 0; n < TN; ++n) {
        union { bf16 b; u16 u; } c; c.u = meanws[(long)(n0 + n) * EE + r];
        mm[n][r] = __bfloat162float(c.b);
        ea[n][r] = edge_attr[(long)(n0 + n) * EE + r];
    }
    __syncthreads();
    float acc[TN];
    float bsr = bs[r];
    #pragma unroll
    for (int n = 0; n < TN; ++n) acc[n] = bsr;
    for (int c = 0; c < EE; ++c) {
        float w = Wst[c * EE + r];
        #pragma unroll
        for (int n = 0; n < TN; ++n) acc[n] += mm[n][c] * w;
    }
    for (int c = 0; c < EE; ++c) {
        float w = Wst[(EE + c) * EE + r];
        #pragma unroll
        for (int n = 0; n < TN; ++n) acc[n] += ea[n][c] * w;
    }
    for (int n = 0; n < TN; ++n)
        outs[(long)(n0 + n) * EE + r] = acc[n];
}

extern "C" void kernel_launch(void* const* d_in, const int* in_sizes, int n_in,
                              void* d_out, int out_size, void* d_ws, size_t ws_size,
                              hipStream_t stream) {
    const float* feature   = (const float*)d_in[0];
    const float* dists_max = (const float*)d_in[1];
    const int* dists_argmax = (const int*)d_in[2];
    const float* edge_attr = (const float*)d_in[3];
    const float* W1 = (const float*)d_in[4];
    const float* b1 = (const float*)d_in[5];
    const float* W2 = (const float*)d_in[6];
    const float* b2 = (const float*)d_in[7];
    const float* Wf = (const float*)d_in[8];
    const float* bf = (const float*)d_in[9];
    const float* Wh = (const float*)d_in[10];
    const float* bh = (const float*)d_in[11];
    const float* Wp = (const float*)d_in[12];
    const float* bp = (const float*)d_in[13];
    const float* Ws = (const float*)d_in[14];
    const float* bs = (const float*)d_in[15];

    float* outpos = (float*)d_out;        // [N,K] f32: d scratch, then pos
    float* outs   = outpos + NK;          // [N,E] f32: g+h2 bf16 scratch, then out_structure
    u16* g  = (u16*)outs;                 // [N,E] bf16  (12.8 MB)
    u16* h2 = g + NE;                     // [N,E] bf16  (12.8 MB) — exactly fills region

    // Workspace (proven size): 0.26 MB f32 weights + 12.8 MB bf16 mean.
    float* Acm  = (float*)d_ws;           // [EE*EE]
    float* Bcm  = Acm + EE * EE;          // [EE*EE]
    float* agf  = Bcm + EE * EE;          // [EE]
    float* bh2f = agf + EE;               // [EE]
    float* Wst  = bh2f + EE;              // [2*EE*EE]
    u16* meanws = (u16*)(Wst + 2 * EE * EE);  // [N*E] bf16

    prep_weights<<<dim3(2 * EE, 2), EE, 0, stream>>>(Wh, Wf, bf, bh, Ws,
                                                     Acm, Bcm, agf, bh2f, Wst);
    dist_mlp<<<(NK + 1023) / 1024, 256, 0, stream>>>(dists_max, W1, b1, W2, b2, outpos);
    proj_gh<<<N_NODES / TN, EE, 0, stream>>>(feature, Acm, Bcm, agf, bh2f, g, h2);
    fused_msg<<<N_NODES / WAVES, 256, 0, stream>>>(dists_argmax, (const u32*)g,
                                                   (const u32*)h2, Wp, bp,
                                                   outpos, (u32*)meanws);
    out_struct<<<N_NODES / TN, EE, 0, stream>>>(meanws, edge_attr, Wst, bs, outs);
}

// Round 7
// 338.075 us; speedup vs baseline: 1.9087x; 1.9087x over previous
//
#include <hip/hip_runtime.h>
#include <hip/hip_bf16.h>

#define N_NODES 50000
#define KK 32
#define EE 128
#define NK (N_NODES * KK)
#define NE (N_NODES * EE)
#define TN 16
#define WAVES 4

typedef __hip_bfloat16 bf16;
typedef unsigned int u32;
typedef unsigned short u16;

// bf16x2 packed in a dword: lo = first element, hi = second
__device__ __forceinline__ float bflo(u32 u) { return __uint_as_float(u << 16); }
__device__ __forceinline__ float bfhi(u32 u) { return __uint_as_float(u & 0xFFFF0000u); }
__device__ __forceinline__ u16 f2bu(float x) {
    union { bf16 b; u16 u; } c; c.b = __float2bfloat16(x); return c.u;
}
__device__ __forceinline__ u32 packbf2(float lo, float hi) {
    return (u32)f2bu(lo) | ((u32)f2bu(hi) << 16);
}

// ---------------------------------------------------------------------------
// Prep: y==0 -> A = WhL@Wf, B = WhR@Wf (column-major [c][r]) + ag/bh2 biases;
//       y==1 -> transpose Ws [128][256] -> Wst [256][128].
// grid (256,2), block 128.
// ---------------------------------------------------------------------------
__global__ void prep_weights(const float* __restrict__ Wh, const float* __restrict__ Wf,
                             const float* __restrict__ bfv, const float* __restrict__ bh,
                             const float* __restrict__ Ws,
                             float* Acm, float* Bcm, float* agf, float* bh2f, float* Wst) {
    int bx = blockIdx.x;
    if (blockIdx.y == 1) {   // transpose Ws: c = bx in [0,256)
        int r = threadIdx.x;
        Wst[bx * EE + r] = Ws[(long)r * (2 * EE) + bx];
        return;
    }
    int m = bx >> 7;
    int r = bx & 127;
    int c = threadIdx.x;
    const float* whrow = Wh + (long)r * (2 * EE) + m * EE;
    float acc = 0.f;
    for (int j = 0; j < EE; ++j)
        acc += whrow[j] * Wf[(long)j * EE + c];
    float* dst = m ? Bcm : Acm;
    dst[c * EE + r] = acc;
    if (c == 0) {
        float accb = 0.f;
        for (int j = 0; j < EE; ++j) accb += whrow[j] * bfv[j];
        if (m) bh2f[r] = accb + bh[r];
        else   agf[r] = accb;
    }
}

// ---------------------------------------------------------------------------
// Distance MLP: d(x) = sum_e W2[e]*relu(W1[e]*x + b1[e]) + b2.
// d written f32 into the out_position region of d_out.
// ---------------------------------------------------------------------------
__global__ __launch_bounds__(256) void dist_mlp(const float* __restrict__ dists,
                                                const float* __restrict__ W1,
                                                const float* __restrict__ b1,
                                                const float* __restrict__ W2,
                                                const float* __restrict__ b2v,
                                                float* __restrict__ dst) {
    __shared__ float4 w4[EE];
    int tid = threadIdx.x;
    if (tid < EE) w4[tid] = make_float4(W1[tid], b1[tid], W2[tid], 0.f);
    __syncthreads();
    float b2s = b2v[0];
    int i0 = (blockIdx.x * 256 + tid) * 4;
    float x[4], acc[4];
    #pragma unroll
    for (int j = 0; j < 4; ++j) {
        int i = i0 + j;
        x[j] = (i < NK) ? dists[i] : 0.f;
        acc[j] = b2s;
    }
    for (int e = 0; e < EE; ++e) {
        float4 w = w4[e];
        #pragma unroll
        for (int j = 0; j < 4; ++j)
            acc[j] += w.z * fmaxf(w.x * x[j] + w.y, 0.f);
    }
    #pragma unroll
    for (int j = 0; j < 4; ++j) {
        int i = i0 + j;
        if (i < NK) dst[i] = acc[j];
    }
}

// ---------------------------------------------------------------------------
// g = feature@A^T + ag, h2 = feature@B^T + bh2, both bf16, packed into the
// out_structure region of d_out. float4 LDS broadcast reads. grid N/TN, blk 128.
// ---------------------------------------------------------------------------
__global__ __launch_bounds__(128) void proj_gh(const float* __restrict__ feature,
                                               const float* __restrict__ Acm,
                                               const float* __restrict__ Bcm,
                                               const float* __restrict__ agf,
                                               const float* __restrict__ bh2f,
                                               u16* __restrict__ g, u16* __restrict__ h2) {
    __shared__ float fl[TN][EE];
    int r = threadIdx.x;
    int n0 = blockIdx.x * TN;
    for (int n = 0; n < TN; ++n)
        fl[n][r] = feature[(long)(n0 + n) * EE + r];
    __syncthreads();
    float accg[TN], acch[TN];
    float ag = agf[r], bh = bh2f[r];
    #pragma unroll
    for (int n = 0; n < TN; ++n) { accg[n] = ag; acch[n] = bh; }
    for (int c4 = 0; c4 < EE; c4 += 4) {
        float a[4], b[4];
        #pragma unroll
        for (int j = 0; j < 4; ++j) {
            a[j] = Acm[(c4 + j) * EE + r];
            b[j] = Bcm[(c4 + j) * EE + r];
        }
        #pragma unroll
        for (int n = 0; n < TN; ++n) {
            float4 f4 = *(const float4*)&fl[n][c4];   // LDS b128 broadcast
            accg[n] += f4.x * a[0] + f4.y * a[1] + f4.z * a[2] + f4.w * a[3];
            acch[n] += f4.x * b[0] + f4.y * b[1] + f4.z * b[2] + f4.w * b[3];
        }
    }
    for (int n = 0; n < TN; ++n) {
        g [(long)(n0 + n) * EE + r] = f2bu(accg[n]);
        h2[(long)(n0 + n) * EE + r] = f2bu(acch[n]);
    }
}

// ---------------------------------------------------------------------------
// Fused gather + relu + Wp-dot + mean. One wave per node; lane handles
// channels (2*lane, 2*lane+1) -> one dword gather per (k,lane). k-loop fully
// unrolled (shfl -> v_readlane). Wp-partials written packed-bf16 to a per-wave
// LDS tile, then a static column-sum transpose reduction (16 writes + 16
// reads + 4 swizzles per wave vs 256 cross-lane ops in the butterfly version).
// grid N/4, block 256; LDS 16.6 KB -> occupancy capped by threads (100%).
// ---------------------------------------------------------------------------
__global__ __launch_bounds__(256) void fused_msg(const int* __restrict__ argmax,
                                                 const u32* __restrict__ g,
                                                 const u32* __restrict__ h2,
                                                 const float* __restrict__ Wp,
                                                 const float* __restrict__ bpv,
                                                 float* outpos,
                                                 u32* __restrict__ meanws) {
    __shared__ u32 tile[WAVES][KK / 2][65];   // [wave][k-pair][src lane], pad 65
    int tid = threadIdx.x;
    int lane = tid & 63;
    int wave = tid >> 6;
    int n = blockIdx.x * WAVES + wave;

    u32 hu = h2[(long)n * (EE / 2) + lane];
    float h0 = bflo(hu), h1 = bfhi(hu);
    float2 wpv = ((const float2*)Wp)[lane];
    float bpf = bpv[0];

    int idxv = 0;
    float dv = 0.f;
    if (lane < KK) {
        idxv = argmax[(long)n * KK + lane];
        dv = outpos[(long)n * KK + lane];   // d (written by dist_mlp)
    }

    float acc0 = 0.f, acc1 = 0.f;
    float ppe = 0.f;
    #pragma unroll
    for (int k = 0; k < KK; ++k) {
        int row = __shfl(idxv, k);    // compile-time k -> v_readlane
        float dk = __shfl(dv, k);
        u32 gu = g[(long)row * (EE / 2) + lane];
        float m0 = fmaxf(dk * bflo(gu) + h0, 0.f);
        float m1 = fmaxf(dk * bfhi(gu) + h1, 0.f);
        acc0 += m0;
        acc1 += m1;
        float p = fmaf(m1, wpv.y, m0 * wpv.x);
        if (k & 1) tile[wave][k >> 1][lane] = packbf2(ppe, p);
        else       ppe = p;
    }
    meanws[(long)n * (EE / 2) + lane] = packbf2(acc0 * (1.f / KK), acc1 * (1.f / KK));

    // Column-sum: lane l sums dword-column d=l&15 over rows j=(l>>4)*16..+15,
    // then fold the 4 lane-groups with two shfl_xor.
    int d = lane & 15;
    int j0 = (lane >> 4) * 16;
    float s0 = 0.f, s1 = 0.f;
    #pragma unroll
    for (int i = 0; i < 16; ++i) {
        u32 v = tile[wave][d][j0 + i];
        s0 += bflo(v);
        s1 += bfhi(v);
    }
    s0 += __shfl_xor(s0, 16);
    s1 += __shfl_xor(s1, 16);
    s0 += __shfl_xor(s0, 32);
    s1 += __shfl_xor(s1, 32);
    if (lane < 16) {
        float2 o = make_float2(s0 + bpf, s1 + bpf);   // k = 2d, 2d+1
        *(float2*)&outpos[(long)n * KK + 2 * d] = o;
    }
}

// ---------------------------------------------------------------------------
// out_structure = [mean | edge_attr] @ Ws^T + bs -> f32, overwrites the
// out_structure region (g/h2 dead). float4 LDS reads. grid N/TN, block 128.
// ---------------------------------------------------------------------------
__global__ __launch_bounds__(128) void out_struct(const u16* __restrict__ meanws,
                                                  const float* __restrict__ edge_attr,
                                                  const float* __restrict__ Wst,
                                                  const float* __restrict__ bs,
                                                  float* __restrict__ outs) {
    __shared__ float mm[TN][EE];
    __shared__ float ea[TN][EE];
    int r = threadIdx.x;
    int n0 = blockIdx.x * TN;
    for (int n = 0; n < TN; ++n) {
        union { bf16 b; u16 u; } c; c.u = meanws[(long)(n0 + n) * EE + r];
        mm[n][r] = __bfloat162float(c.b);
        ea[n][r] = edge_attr[(long)(n0 + n) * EE + r];
    }
    __syncthreads();
    float acc[TN];
    float bsr = bs[r];
    #pragma unroll
    for (int n = 0; n < TN; ++n) acc[n] = bsr;
    for (int c4 = 0; c4 < EE; c4 += 4) {
        float w[4], w2[4];
        #pragma unroll
        for (int j = 0; j < 4; ++j) {
            w[j]  = Wst[(c4 + j) * EE + r];
            w2[j] = Wst[(EE + c4 + j) * EE + r];
        }
        #pragma unroll
        for (int n = 0; n < TN; ++n) {
            float4 m4 = *(const float4*)&mm[n][c4];
            float4 e4 = *(const float4*)&ea[n][c4];
            acc[n] += m4.x * w[0] + m4.y * w[1] + m4.z * w[2] + m4.w * w[3]
                    + e4.x * w2[0] + e4.y * w2[1] + e4.z * w2[2] + e4.w * w2[3];
        }
    }
    for (int n = 0; n < TN; ++n)
        outs[(long)(n0 + n) * EE + r] = acc[n];
}

extern "C" void kernel_launch(void* const* d_in, const int* in_sizes, int n_in,
                              void* d_out, int out_size, void* d_ws, size_t ws_size,
                              hipStream_t stream) {
    const float* feature   = (const float*)d_in[0];
    const float* dists_max = (const float*)d_in[1];
    const int* dists_argmax = (const int*)d_in[2];
    const float* edge_attr = (const float*)d_in[3];
    const float* W1 = (const float*)d_in[4];
    const float* b1 = (const float*)d_in[5];
    const float* W2 = (const float*)d_in[6];
    const float* b2 = (const float*)d_in[7];
    const float* Wf = (const float*)d_in[8];
    const float* bf = (const float*)d_in[9];
    const float* Wh = (const float*)d_in[10];
    const float* bh = (const float*)d_in[11];
    const float* Wp = (const float*)d_in[12];
    const float* bp = (const float*)d_in[13];
    const float* Ws = (const float*)d_in[14];
    const float* bs = (const float*)d_in[15];

    float* outpos = (float*)d_out;        // [N,K] f32: d scratch, then pos
    float* outs   = outpos + NK;          // [N,E] f32: g+h2 bf16 scratch, then out_structure
    u16* g  = (u16*)outs;                 // [N,E] bf16  (12.8 MB)
    u16* h2 = g + NE;                     // [N,E] bf16  (12.8 MB) — exactly fills region

    // Workspace (proven size): 0.26 MB f32 weights + 12.8 MB bf16 mean.
    float* Acm  = (float*)d_ws;           // [EE*EE]
    float* Bcm  = Acm + EE * EE;          // [EE*EE]
    float* agf  = Bcm + EE * EE;          // [EE]
    float* bh2f = agf + EE;               // [EE]
    float* Wst  = bh2f + EE;              // [2*EE*EE]
    u16* meanws = (u16*)(Wst + 2 * EE * EE);  // [N*E] bf16

    prep_weights<<<dim3(2 * EE, 2), EE, 0, stream>>>(Wh, Wf, bf, bh, Ws,
                                                     Acm, Bcm, agf, bh2f, Wst);
    dist_mlp<<<(NK + 1023) / 1024, 256, 0, stream>>>(dists_max, W1, b1, W2, b2, outpos);
    proj_gh<<<N_NODES / TN, EE, 0, stream>>>(feature, Acm, Bcm, agf, bh2f, g, h2);
    fused_msg<<<N_NODES / WAVES, 256, 0, stream>>>(dists_argmax, (const u32*)g,
                                                   (const u32*)h2, Wp, bp,
                                                   outpos, (u32*)meanws);
    out_struct<<<N_NODES / TN, EE, 0, stream>>>(meanws, edge_attr, Wst, bs, outs);
}

// Round 8
// 228.630 us; speedup vs baseline: 2.8224x; 1.4787x over previous
//
#include <hip/hip_runtime.h>
#include <hip/hip_bf16.h>

#define N_NODES 50000
#define KK 32
#define EE 128
#define NK (N_NODES * KK)
#define NE (N_NODES * EE)
#define WAVES 4
#define PR 32   // rows per GEMM block

typedef __hip_bfloat16 bf16;
typedef unsigned int u32;
typedef unsigned short u16;
typedef __attribute__((ext_vector_type(8))) short bf16x8;
typedef __attribute__((ext_vector_type(4))) float f32x4;

__device__ __forceinline__ float bflo(u32 u) { return __uint_as_float(u << 16); }
__device__ __forceinline__ float bfhi(u32 u) { return __uint_as_float(u & 0xFFFF0000u); }
__device__ __forceinline__ u16 f2bu(float x) {
    union { bf16 b; u16 u; } c; c.b = __float2bfloat16(x); return c.u;
}
__device__ __forceinline__ u32 packbf2(float lo, float hi) {
    return (u32)f2bu(lo) | ((u32)f2bu(hi) << 16);
}

// ---------------------------------------------------------------------------
// Prep: A = WhL@Wf, B = WhR@Wf (column-major [c][r], f32) + ag/bh2 biases.
// grid 256, block 128.
// ---------------------------------------------------------------------------
__global__ void prep_weights(const float* __restrict__ Wh, const float* __restrict__ Wf,
                             const float* __restrict__ bfv, const float* __restrict__ bh,
                             float* Acm, float* Bcm, float* agf, float* bh2f) {
    int bx = blockIdx.x;
    int m = bx >> 7;
    int r = bx & 127;
    int c = threadIdx.x;
    const float* whrow = Wh + (long)r * (2 * EE) + m * EE;
    float acc = 0.f;
    for (int j = 0; j < EE; ++j)
        acc += whrow[j] * Wf[(long)j * EE + c];
    float* dst = m ? Bcm : Acm;
    dst[c * EE + r] = acc;
    if (c == 0) {
        float accb = 0.f;
        for (int j = 0; j < EE; ++j) accb += whrow[j] * bfv[j];
        if (m) bh2f[r] = accb + bh[r];
        else   agf[r] = accb;
    }
}

// ---------------------------------------------------------------------------
// Pack MFMA B-fragments (bf16, per-lane order so a frag = one 16B load).
// Wghp: K=128,N=256 from Acm|Bcm (4 k-steps x 16 col-tiles).
// Wstp: K=256,N=128 from Ws directly (8 k-steps x 8 col-tiles).
// frag element: b[jj] = B[k0 + (lane>>4)*8 + jj][j0 + (lane&15)].
// grid 128, block 256.
// ---------------------------------------------------------------------------
__global__ void pack_frags(const float* __restrict__ Acm, const float* __restrict__ Bcm,
                           const float* __restrict__ Ws,
                           u16* __restrict__ Wghp, u16* __restrict__ Wstp) {
    int b = blockIdx.x;
    for (int f = threadIdx.x; f < 512; f += 256) {
        int lane = f >> 3, jj = f & 7;
        int col = lane & 15, quad = lane >> 4;
        if (b < 64) {                       // Wgh: t=b>>4 (0..3), jt=b&15 (0..15)
            int t = b >> 4, jt = b & 15;
            int j = jt * 16 + col;
            int k = t * 32 + quad * 8 + jj;
            float v = (j < EE) ? Acm[k * EE + j] : Bcm[k * EE + (j - EE)];
            Wghp[(long)b * 512 + f] = f2bu(v);
        } else {                            // Wst: t=bb>>3 (0..7), jt=bb&7 (0..7)
            int bb = b - 64, t = bb >> 3, jt = bb & 7;
            int r = jt * 16 + col;
            int c = t * 32 + quad * 8 + jj;
            Wstp[(long)bb * 512 + f] = f2bu(Ws[(long)r * (2 * EE) + c]);
        }
    }
}

// ---------------------------------------------------------------------------
// Distance MLP: d(x) = sum_e W2[e]*relu(W1[e]*x + b1[e]) + b2.
// d written f32 into the out_position region of d_out.
// ---------------------------------------------------------------------------
__global__ __launch_bounds__(256) void dist_mlp(const float* __restrict__ dists,
                                                const float* __restrict__ W1,
                                                const float* __restrict__ b1,
                                                const float* __restrict__ W2,
                                                const float* __restrict__ b2v,
                                                float* __restrict__ dst) {
    __shared__ float4 w4[EE];
    int tid = threadIdx.x;
    if (tid < EE) w4[tid] = make_float4(W1[tid], b1[tid], W2[tid], 0.f);
    __syncthreads();
    float b2s = b2v[0];
    int i0 = (blockIdx.x * 256 + tid) * 4;
    float x[4], acc[4];
    #pragma unroll
    for (int j = 0; j < 4; ++j) {
        int i = i0 + j;
        x[j] = (i < NK) ? dists[i] : 0.f;
        acc[j] = b2s;
    }
    for (int e = 0; e < EE; ++e) {
        float4 w = w4[e];
        #pragma unroll
        for (int j = 0; j < 4; ++j)
            acc[j] += w.z * fmaxf(w.x * x[j] + w.y, 0.f);
    }
    #pragma unroll
    for (int j = 0; j < 4; ++j) {
        int i = i0 + j;
        if (i < NK) dst[i] = acc[j];
    }
}

// ---------------------------------------------------------------------------
// MFMA GEMM: [g|h2] = feature @ [A;B]^T + bias  -> bf16 into out_structure
// region. Block: 32 rows x 256 cols, 4 waves x (2 m-tiles x 4 j-tiles).
// Feature staged bf16 in LDS, row stride 68 u32 (2-way bank alias = free).
// grid ceil(N/32), block 256.
// ---------------------------------------------------------------------------
__global__ __launch_bounds__(256) void proj_gh_mfma(const float* __restrict__ feature,
                                                    const u16* __restrict__ Wghp,
                                                    const float* __restrict__ agf,
                                                    const float* __restrict__ bh2f,
                                                    u16* __restrict__ g,
                                                    u16* __restrict__ h2) {
    __shared__ u32 ft[PR * 68];
    int tid = threadIdx.x;
    int n0 = blockIdx.x * PR;
    for (int idx = tid; idx < PR * 32; idx += 256) {   // float4 units, 32/row
        int rr = idx >> 5, c4 = idx & 31;
        long row = n0 + rr; if (row >= N_NODES) row = N_NODES - 1;
        float4 v = ((const float4*)(feature + row * EE))[c4];
        ft[rr * 68 + 2 * c4]     = packbf2(v.x, v.y);
        ft[rr * 68 + 2 * c4 + 1] = packbf2(v.z, v.w);
    }
    __syncthreads();
    int lane = tid & 63, wave = tid >> 6;
    int col = lane & 15, quad = lane >> 4;
    f32x4 acc[2][4] = {};
    #pragma unroll
    for (int t = 0; t < 4; ++t) {
        bf16x8 a0 = *(const bf16x8*)&ft[col * 68 + t * 16 + quad * 4];
        bf16x8 a1 = *(const bf16x8*)&ft[(16 + col) * 68 + t * 16 + quad * 4];
        #pragma unroll
        for (int jt = 0; jt < 4; ++jt) {
            int jtg = wave * 4 + jt;
            bf16x8 b = *(const bf16x8*)&Wghp[((long)(t * 16 + jtg) * 64 + lane) * 8];
            acc[0][jt] = __builtin_amdgcn_mfma_f32_16x16x32_bf16(a0, b, acc[0][jt], 0, 0, 0);
            acc[1][jt] = __builtin_amdgcn_mfma_f32_16x16x32_bf16(a1, b, acc[1][jt], 0, 0, 0);
        }
    }
    #pragma unroll
    for (int jt = 0; jt < 4; ++jt) {
        int j = wave * 64 + jt * 16 + col;             // 0..255
        float bias = (j < EE) ? agf[j] : bh2f[j - EE];
        u16* dst = (j < EE) ? (g + j) : (h2 + (j - EE));
        #pragma unroll
        for (int mt = 0; mt < 2; ++mt)
            #pragma unroll
            for (int i = 0; i < 4; ++i) {
                long row = n0 + mt * 16 + quad * 4 + i;
                if (row < N_NODES) dst[row * EE] = f2bu(acc[mt][jt][i] + bias);
            }
    }
}

// ---------------------------------------------------------------------------
// Fused gather + relu + Wp-dot + mean (unchanged from R7 win).
// grid N/4, block 256.
// ---------------------------------------------------------------------------
__global__ __launch_bounds__(256) void fused_msg(const int* __restrict__ argmax,
                                                 const u32* __restrict__ g,
                                                 const u32* __restrict__ h2,
                                                 const float* __restrict__ Wp,
                                                 const float* __restrict__ bpv,
                                                 float* outpos,
                                                 u32* __restrict__ meanws) {
    __shared__ u32 tile[WAVES][KK / 2][65];
    int tid = threadIdx.x;
    int lane = tid & 63;
    int wave = tid >> 6;
    int n = blockIdx.x * WAVES + wave;

    u32 hu = h2[(long)n * (EE / 2) + lane];
    float h0 = bflo(hu), h1 = bfhi(hu);
    float2 wpv = ((const float2*)Wp)[lane];
    float bpf = bpv[0];

    int idxv = 0;
    float dv = 0.f;
    if (lane < KK) {
        idxv = argmax[(long)n * KK + lane];
        dv = outpos[(long)n * KK + lane];
    }

    float acc0 = 0.f, acc1 = 0.f;
    float ppe = 0.f;
    #pragma unroll
    for (int k = 0; k < KK; ++k) {
        int row = __shfl(idxv, k);
        float dk = __shfl(dv, k);
        u32 gu = g[(long)row * (EE / 2) + lane];
        float m0 = fmaxf(dk * bflo(gu) + h0, 0.f);
        float m1 = fmaxf(dk * bfhi(gu) + h1, 0.f);
        acc0 += m0;
        acc1 += m1;
        float p = fmaf(m1, wpv.y, m0 * wpv.x);
        if (k & 1) tile[wave][k >> 1][lane] = packbf2(ppe, p);
        else       ppe = p;
    }
    meanws[(long)n * (EE / 2) + lane] = packbf2(acc0 * (1.f / KK), acc1 * (1.f / KK));

    int d = lane & 15;
    int j0 = (lane >> 4) * 16;
    float s0 = 0.f, s1 = 0.f;
    #pragma unroll
    for (int i = 0; i < 16; ++i) {
        u32 v = tile[wave][d][j0 + i];
        s0 += bflo(v);
        s1 += bfhi(v);
    }
    s0 += __shfl_xor(s0, 16);
    s1 += __shfl_xor(s1, 16);
    s0 += __shfl_xor(s0, 32);
    s1 += __shfl_xor(s1, 32);
    if (lane < 16) {
        float2 o = make_float2(s0 + bpf, s1 + bpf);
        *(float2*)&outpos[(long)n * KK + 2 * d] = o;
    }
}

// ---------------------------------------------------------------------------
// MFMA GEMM: out_structure = [mean | ea] @ Ws^T + bs -> f32, overwrites the
// out_structure region. Block: 32 rows x 128 cols, K=256 (8 k-steps),
// 4 waves x (2 m-tiles x 2 j-tiles). A staged bf16 in LDS, stride 132 u32.
// grid ceil(N/32), block 256.
// ---------------------------------------------------------------------------
__global__ __launch_bounds__(256) void out_struct_mfma(const u16* __restrict__ meanws,
                                                       const float* __restrict__ edge_attr,
                                                       const u16* __restrict__ Wstp,
                                                       const float* __restrict__ bs,
                                                       float* __restrict__ outs) {
    __shared__ u32 at[PR * 132];
    int tid = threadIdx.x;
    int n0 = blockIdx.x * PR;
    for (int idx = tid; idx < PR * 64; idx += 256) {   // mean: u32 units, 64/row
        int rr = idx >> 6, c = idx & 63;
        long row = n0 + rr; if (row >= N_NODES) row = N_NODES - 1;
        at[rr * 132 + c] = ((const u32*)meanws)[row * 64 + c];
    }
    for (int idx = tid; idx < PR * 32; idx += 256) {   // ea: float4 units, 32/row
        int rr = idx >> 5, c4 = idx & 31;
        long row = n0 + rr; if (row >= N_NODES) row = N_NODES - 1;
        float4 v = ((const float4*)(edge_attr + row * EE))[c4];
        at[rr * 132 + 64 + 2 * c4]     = packbf2(v.x, v.y);
        at[rr * 132 + 64 + 2 * c4 + 1] = packbf2(v.z, v.w);
    }
    __syncthreads();
    int lane = tid & 63, wave = tid >> 6;
    int col = lane & 15, quad = lane >> 4;
    f32x4 acc[2][2] = {};
    #pragma unroll
    for (int t = 0; t < 8; ++t) {
        bf16x8 a0 = *(const bf16x8*)&at[col * 132 + t * 16 + quad * 4];
        bf16x8 a1 = *(const bf16x8*)&at[(16 + col) * 132 + t * 16 + quad * 4];
        #pragma unroll
        for (int jt = 0; jt < 2; ++jt) {
            int jtg = wave * 2 + jt;
            bf16x8 b = *(const bf16x8*)&Wstp[((long)(t * 8 + jtg) * 64 + lane) * 8];
            acc[0][jt] = __builtin_amdgcn_mfma_f32_16x16x32_bf16(a0, b, acc[0][jt], 0, 0, 0);
            acc[1][jt] = __builtin_amdgcn_mfma_f32_16x16x32_bf16(a1, b, acc[1][jt], 0, 0, 0);
        }
    }
    #pragma unroll
    for (int jt = 0; jt < 2; ++jt) {
        int j = wave * 32 + jt * 16 + col;             // 0..127
        float bias = bs[j];
        #pragma unroll
        for (int mt = 0; mt < 2; ++mt)
            #pragma unroll
            for (int i = 0; i < 4; ++i) {
                long row = n0 + mt * 16 + quad * 4 + i;
                if (row < N_NODES) outs[row * EE + j] = acc[mt][jt][i] + bias;
            }
    }
}

extern "C" void kernel_launch(void* const* d_in, const int* in_sizes, int n_in,
                              void* d_out, int out_size, void* d_ws, size_t ws_size,
                              hipStream_t stream) {
    const float* feature   = (const float*)d_in[0];
    const float* dists_max = (const float*)d_in[1];
    const int* dists_argmax = (const int*)d_in[2];
    const float* edge_attr = (const float*)d_in[3];
    const float* W1 = (const float*)d_in[4];
    const float* b1 = (const float*)d_in[5];
    const float* W2 = (const float*)d_in[6];
    const float* b2 = (const float*)d_in[7];
    const float* Wf = (const float*)d_in[8];
    const float* bf = (const float*)d_in[9];
    const float* Wh = (const float*)d_in[10];
    const float* bh = (const float*)d_in[11];
    const float* Wp = (const float*)d_in[12];
    const float* bp = (const float*)d_in[13];
    const float* Ws = (const float*)d_in[14];
    const float* bs = (const float*)d_in[15];

    float* outpos = (float*)d_out;        // [N,K] f32: d scratch, then pos
    float* outs   = outpos + NK;          // [N,E] f32: g+h2 bf16 scratch, then out_structure
    u16* g  = (u16*)outs;                 // [N,E] bf16  (12.8 MB)
    u16* h2 = g + NE;                     // [N,E] bf16  (12.8 MB)

    // Workspace (same proven footprint as R5-R7): 0.26 MB f32 + 12.8 MB bf16.
    float* Acm  = (float*)d_ws;           // [EE*EE]
    float* Bcm  = Acm + EE * EE;          // [EE*EE]
    float* agf  = Bcm + EE * EE;          // [EE]
    float* bh2f = agf + EE;               // [EE]
    float* Wst  = bh2f + EE;              // [2*EE*EE] area, reused for packs:
    u16* Wghp = (u16*)Wst;                //   64 KB (4*16 frag-tiles)
    u16* Wstp = Wghp + 64 * 512;          //   64 KB (8*8 frag-tiles)
    u16* meanws = (u16*)(Wst + 2 * EE * EE);  // [N*E] bf16 (unchanged offset)

    int gemm_blocks = (N_NODES + PR - 1) / PR;
    prep_weights<<<2 * EE, EE, 0, stream>>>(Wh, Wf, bf, bh, Acm, Bcm, agf, bh2f);
    pack_frags<<<128, 256, 0, stream>>>(Acm, Bcm, Ws, Wghp, Wstp);
    dist_mlp<<<(NK + 1023) / 1024, 256, 0, stream>>>(dists_max, W1, b1, W2, b2, outpos);
    proj_gh_mfma<<<gemm_blocks, 256, 0, stream>>>(feature, Wghp, agf, bh2f, g, h2);
    fused_msg<<<N_NODES / WAVES, 256, 0, stream>>>(dists_argmax, (const u32*)g,
                                                   (const u32*)h2, Wp, bp,
                                                   outpos, (u32*)meanws);
    out_struct_mfma<<<gemm_blocks, 256, 0, stream>>>(meanws, edge_attr, Wstp, bs, outs);
}